// Round 1
// baseline (498.293 us; speedup 1.0000x reference)
//
#include <hip/hip_runtime.h>
#include <hip/hip_bf16.h>
#include <stdint.h>

#define NB 50000     // batch rows
#define KN 32        // neighbors
#define NN 200000    // nodes
#define DD 256       // feature dim
#define EE 256       // embed dim
// GEMM: M=NB, K=512, N=EE

typedef unsigned short u16;
typedef __attribute__((ext_vector_type(8))) short bf16x8;
typedef __attribute__((ext_vector_type(4))) float f32x4;

static __device__ __forceinline__ u16 f2bf(float f) {
  __hip_bfloat16 h = __float2bfloat16(f);
  return *reinterpret_cast<u16*>(&h);
}
static __device__ __forceinline__ float bf2f(u16 u) {
  return __uint_as_float(((unsigned)u) << 16);
}

// ---------------- kernel 1: Wc = W_init @ Wf_top (f32), bc = b_init @ Wf_top + b_final
// grid 257 blocks x 256 threads. block d<256 -> row d of Wc; block 256 -> bc.
__global__ void wc_kernel(const float* __restrict__ Wi, const float* __restrict__ bi,
                          const float* __restrict__ Wf, const float* __restrict__ bf,
                          float* __restrict__ Wc, float* __restrict__ bc) {
  const int e = threadIdx.x;
  const int d = blockIdx.x;
  if (d < DD) {
    const float* wrow = Wi + (size_t)d * DD;
    float acc = 0.f;
    for (int t = 0; t < DD; ++t)
      acc = fmaf(wrow[t], Wf[(size_t)t * EE + e], acc);
    Wc[(size_t)d * EE + e] = acc;
  } else {
    float acc = bf[e];
    for (int t = 0; t < DD; ++t)
      acc = fmaf(bi[t], Wf[(size_t)t * EE + e], acc);
    bc[e] = acc;
  }
}

// ---------------- kernel 2: build Bt[e][0..511] bf16 = [Wc[:,e] | Wf_bot[:,e]]
// grid 256 blocks (e) x 256 threads (d)
__global__ void wt_kernel(const float* __restrict__ Wc, const float* __restrict__ Wf,
                          u16* __restrict__ Bt) {
  const int e = blockIdx.x, d = threadIdx.x;
  Bt[(size_t)e * 512 + d]       = f2bf(Wc[(size_t)d * EE + e]);
  Bt[(size_t)e * 512 + 256 + d] = f2bf(Wf[(size_t)(DD + d) * EE + e]);
}

// ---------------- kernel 3: features f32 -> bf16 (n4 float4 chunks)
__global__ void cvt_kernel(const float* __restrict__ in, u16* __restrict__ out, int n4) {
  int i = blockIdx.x * blockDim.x + threadIdx.x;
  const int stride = gridDim.x * blockDim.x;
  for (; i < n4; i += stride) {
    float4 v = ((const float4*)in)[i];
    ushort4 o;
    o.x = f2bf(v.x); o.y = f2bf(v.y); o.z = f2bf(v.z); o.w = f2bf(v.w);
    ((ushort4*)out)[i] = o;
  }
}

// ---------------- kernel 4: aggregation. one wave per row b. writes combined[b][512] bf16
// combined layout: [0:256] = raw self features, [256:512] = weighted-mean neighbor feats
template<int BF16FEAT>
__global__ void agg_kernel(const int* __restrict__ nodes,
                           const int* __restrict__ nidx,
                           const float* __restrict__ nw,
                           const void* __restrict__ featv,
                           u16* __restrict__ combined) {
  const int wave = threadIdx.x >> 6;
  const int lane = threadIdx.x & 63;
  const int b = blockIdx.x * 4 + wave;

  int idx = 0; float w = 0.f;
  if (lane < KN) {
    idx = nidx[(size_t)b * KN + lane];
    w   = nw[(size_t)b * KN + lane];
  }
  float s = w;
  #pragma unroll
  for (int off = 32; off >= 1; off >>= 1) s += __shfl_xor(s, off);
  const float inv = 1.f / s;

  float a0 = 0.f, a1 = 0.f, a2 = 0.f, a3 = 0.f;
  if (BF16FEAT) {
    const u16* f = (const u16*)featv;
    #pragma unroll
    for (int k = 0; k < KN; ++k) {
      const int   ik = __builtin_amdgcn_readlane(idx, k);
      const float wk = __uint_as_float(__builtin_amdgcn_readlane(__float_as_uint(w), k)) * inv;
      ushort4 v = *(const ushort4*)(f + (size_t)ik * DD + lane * 4);
      a0 = fmaf(wk, bf2f(v.x), a0);
      a1 = fmaf(wk, bf2f(v.y), a1);
      a2 = fmaf(wk, bf2f(v.z), a2);
      a3 = fmaf(wk, bf2f(v.w), a3);
    }
    const int node = nodes[b];
    ushort4 sv = *(const ushort4*)(f + (size_t)node * DD + lane * 4);
    ushort4 nv; nv.x = f2bf(a0); nv.y = f2bf(a1); nv.z = f2bf(a2); nv.w = f2bf(a3);
    *(ushort4*)(combined + (size_t)b * 512 + lane * 4) = sv;
    *(ushort4*)(combined + (size_t)b * 512 + 256 + lane * 4) = nv;
  } else {
    const float* f = (const float*)featv;
    #pragma unroll 8
    for (int k = 0; k < KN; ++k) {
      const int   ik = __builtin_amdgcn_readlane(idx, k);
      const float wk = __uint_as_float(__builtin_amdgcn_readlane(__float_as_uint(w), k)) * inv;
      float4 v = *(const float4*)(f + (size_t)ik * DD + lane * 4);
      a0 = fmaf(wk, v.x, a0);
      a1 = fmaf(wk, v.y, a1);
      a2 = fmaf(wk, v.z, a2);
      a3 = fmaf(wk, v.w, a3);
    }
    const int node = nodes[b];
    float4 sv = *(const float4*)(f + (size_t)node * DD + lane * 4);
    ushort4 so; so.x = f2bf(sv.x); so.y = f2bf(sv.y); so.z = f2bf(sv.z); so.w = f2bf(sv.w);
    ushort4 nv; nv.x = f2bf(a0);   nv.y = f2bf(a1);   nv.z = f2bf(a2);   nv.w = f2bf(a3);
    *(ushort4*)(combined + (size_t)b * 512 + lane * 4) = so;
    *(ushort4*)(combined + (size_t)b * 512 + 256 + lane * 4) = nv;
  }
}

// ---------------- kernel 5: GEMM  out = swish(combined @ Bt^T + bc)
// A [M][512] bf16 row-major, Bt [256][512] bf16 (N-major, K-contiguous)
#define BM 128
#define BN 64
#define BKK 32
#define LDT 72   // LDS row stride in u16 (144 B: 16B-aligned, ~2-way banks)

__global__ __launch_bounds__(256) void gemm_kernel(const u16* __restrict__ A,
                                                   const u16* __restrict__ Bt,
                                                   const float* __restrict__ bc,
                                                   float* __restrict__ out, int M) {
  __shared__ u16 As[BM][LDT];
  __shared__ u16 Bs[BN][LDT];
  const int tid = threadIdx.x;
  const int wv = tid >> 6, lane = tid & 63;
  const int m0 = blockIdx.x * BM;
  const int n0 = blockIdx.y * BN;

  f32x4 acc[2][4];
  #pragma unroll
  for (int i = 0; i < 2; ++i)
    #pragma unroll
    for (int j = 0; j < 4; ++j) acc[i][j] = (f32x4){0.f, 0.f, 0.f, 0.f};

  const int ar0 = tid >> 2;     // 0..63
  const int as0 = tid & 3;      // 16B segment within 64B row-chunk
  int ga0 = m0 + ar0;      if (ga0 >= M) ga0 = M - 1;
  int ga1 = m0 + 64 + ar0; if (ga1 >= M) ga1 = M - 1;
  const u16* pA0 = A + (size_t)ga0 * 512 + as0 * 8;
  const u16* pA1 = A + (size_t)ga1 * 512 + as0 * 8;
  const u16* pB  = Bt + (size_t)(n0 + ar0) * 512 + as0 * 8;

  const int frow = lane & 15;
  const int fk = (lane >> 4) * 8;

  for (int k0 = 0; k0 < 512; k0 += BKK) {
    uint4 a0 = *(const uint4*)(pA0 + k0);
    uint4 a1 = *(const uint4*)(pA1 + k0);
    uint4 b0 = *(const uint4*)(pB + k0);
    __syncthreads();
    *(uint4*)&As[ar0][as0 * 8] = a0;
    *(uint4*)&As[64 + ar0][as0 * 8] = a1;
    *(uint4*)&Bs[ar0][as0 * 8] = b0;
    __syncthreads();

    bf16x8 af[2], bq[4];
    #pragma unroll
    for (int mf = 0; mf < 2; ++mf)
      af[mf] = *(const bf16x8*)&As[wv * 32 + mf * 16 + frow][fk];
    #pragma unroll
    for (int nf = 0; nf < 4; ++nf)
      bq[nf] = *(const bf16x8*)&Bs[nf * 16 + frow][fk];
    #pragma unroll
    for (int mf = 0; mf < 2; ++mf)
      #pragma unroll
      for (int nf = 0; nf < 4; ++nf)
        acc[mf][nf] = __builtin_amdgcn_mfma_f32_16x16x32_bf16(af[mf], bq[nf], acc[mf][nf], 0, 0, 0);
  }

  const int fcol = lane & 15;
  const int frq = (lane >> 4) * 4;
  #pragma unroll
  for (int nf = 0; nf < 4; ++nf) {
    const int col = n0 + nf * 16 + fcol;
    const float bias = bc[col];
    #pragma unroll
    for (int mf = 0; mf < 2; ++mf) {
      #pragma unroll
      for (int i = 0; i < 4; ++i) {
        const int row = m0 + wv * 32 + mf * 16 + frq + i;
        if (row < M) {
          const float z = acc[mf][nf][i] + bias;
          out[(size_t)row * EE + col] = z * (1.f / (1.f + __expf(-z)));
        }
      }
    }
  }
}

extern "C" void kernel_launch(void* const* d_in, const int* in_sizes, int n_in,
                              void* d_out, int out_size, void* d_ws, size_t ws_size,
                              hipStream_t stream) {
  const int*   nodes = (const int*)d_in[0];
  const int*   nidx  = (const int*)d_in[1];
  const float* nw    = (const float*)d_in[2];
  const float* feat  = (const float*)d_in[3];
  const float* Wi    = (const float*)d_in[4];
  const float* bi    = (const float*)d_in[5];
  const float* Wf    = (const float*)d_in[6];
  const float* bf    = (const float*)d_in[7];
  float* out = (float*)d_out;

  char* ws = (char*)d_ws;
  // layout (all 16B aligned)
  const size_t OFF_COMB = 0;                         // NB*512*2 = 51,200,000
  const size_t OFF_WC   = 51200000;                  // 256*256*4 = 262,144
  const size_t OFF_BC   = 51462144;                  // 1,024
  const size_t OFF_BT   = 51463168;                  // 256*512*2 = 262,144
  const size_t OFF_FB   = 51725312;                  // NN*DD*2 = 102,400,000
  const size_t NEED_BF16 = OFF_FB + (size_t)NN * DD * 2;

  u16*   combined = (u16*)(ws + OFF_COMB);
  float* Wc       = (float*)(ws + OFF_WC);
  float* bc       = (float*)(ws + OFF_BC);
  u16*   Bt       = (u16*)(ws + OFF_BT);
  u16*   fb       = (u16*)(ws + OFF_FB);

  const bool bf16feat = (ws_size >= NEED_BF16);

  wc_kernel<<<DD + 1, 256, 0, stream>>>(Wi, bi, Wf, bf, Wc, bc);
  wt_kernel<<<EE, 256, 0, stream>>>(Wc, Wf, Bt);

  if (bf16feat) {
    cvt_kernel<<<2048, 256, 0, stream>>>(feat, fb, NN * DD / 4);
    agg_kernel<1><<<NB / 4, 256, 0, stream>>>(nodes, nidx, nw, fb, combined);
  } else {
    agg_kernel<0><<<NB / 4, 256, 0, stream>>>(nodes, nidx, nw, feat, combined);
  }

  gemm_kernel<<<dim3((NB + BM - 1) / BM, EE / BN), 256, 0, stream>>>(combined, Bt, bc, out, NB);
}